// Round 15
// baseline (1533.602 us; speedup 1.0000x reference)
//
#include <hip/hip_runtime.h>
#include <stdint.h>

#define BETA 0.9f

// ---------------------------------------------------------------------------
// Kernel 1: transpose fw1 (256, 1152) -> fw1T (1152, 256) so the fc1 spike
// row-gather is coalesced (row i = 256 contiguous floats = 1KB).
// ---------------------------------------------------------------------------
__global__ void transpose_fw1(const float* __restrict__ A, float* __restrict__ At) {
    __shared__ float tile[32][33];
    const int i0 = blockIdx.x * 32;   // i dim (1152)
    const int j0 = blockIdx.y * 32;   // j dim (256)
    const int tx = threadIdx.x, ty = threadIdx.y;
    for (int r = ty; r < 32; r += 8)
        tile[r][tx] = A[(j0 + r) * 1152 + i0 + tx];      // coalesced read over i
    __syncthreads();
    for (int r = ty; r < 32; r += 8)
        At[(i0 + r) * 256 + j0 + tx] = tile[tx][r];      // coalesced write over j
}

// ---------------------------------------------------------------------------
// Kernel 2: whole SNN. R15 (on R14's pipelined 3-barrier layout):
//  - fc1: the 3 per-l while loops merged into ONE prioritized scalar walk
//    (mk0 -> mk1 -> mk2, fixed segments, branchless selects in SGPRs): serial
//    L2 rounds ceil(S/4) instead of sum of per-l ceils (~6.5 -> ~5), and all
//    3 mask broadcasts issue together. Add order unchanged -> bit-exact.
//    (NOT R13's dynamic ++l scan, which could walk past masks[17].)
//  - amdgpu_waves_per_eu(6,6): probe whether exact-bound lifts the 40-VGPR
//    pin causing the persistent ~3MB scratch (WRITE 7872 vs clean 4800).
// ---------------------------------------------------------------------------
__global__ __launch_bounds__(768)
__attribute__((amdgpu_waves_per_eu(6, 6)))
void snn_main(
    const float* __restrict__ x,      // (1024, 1, 30, 100)
    const float* __restrict__ w1, const float* __restrict__ b1,
    const float* __restrict__ w2, const float* __restrict__ b2,
    const float* __restrict__ w3, const float* __restrict__ b3,
    const float* __restrict__ fw1T,   // (1152, 256) transposed
    const float* __restrict__ fb1,
    const float* __restrict__ fw2, const float* __restrict__ fb2,
    float* __restrict__ out)          // (100, 1024, 10)
{
    const int b    = blockIdx.x;
    const int tid  = threadIdx.x;
    const int e    = (tid >= 384) ? 1 : 0;   // element slot (waves 0-5 / 6-11)
    const int tl   = tid - 384 * e;          // per-element thread id (0..383)
    const int lane = tid & 63;               // hw-wave lane
    const int ew   = tl >> 6;                // per-element wave 0..5

    __shared__ float w2L[16 * 5 * 32];      // [(ci*5+k)*32 + c2]  10 KB
    __shared__ float w3L[32 * 3 * 64];      // [(ci*3+k)*64 + c3]  24 KB
    __shared__ float pacc[2][6][256];       // fc1 per-wave partials  12 KB
    __shared__ float s1e[2][2][16 * 24 + 8];// [e][parity]  6.3 KB
    __shared__ float s4[2][256];
    __shared__ unsigned long long masks[2][18];  // s3 spikes (bit = channel)
    __shared__ unsigned int rm1[2][2][16];  // s1 row masks (bit l), parity
    __shared__ unsigned int cm2[2][2][20];  // s2 per-l channel masks, parity

    // ---- static per-thread roles (within element, 6 waves) ----
    const int c1 = tl & 15;             // conv1: channel (all 384 active)
    const int l1 = tl >> 4;             // conv1: l (0..23), exactly one each
    const int c2 = tl & 31;             // conv2: channel
    const int g2 = tl >> 5;             // conv2: l-group 0..11 (10-11 idle)
    const int l02 = 2 * g2;             // even -> float2-aligned windows
    const bool c2on = (g2 < 10);        // wave-5 halves idle (uniform per half)
    const unsigned wmask2 = c2on ? (0x3Fu << l02) : 0u;
    const int c3 = lane;                // conv3: out channel
    const int l03 = ew * 3;             // conv3: 3 positions per wave (uniform)

    // ---- stage weights into LDS (shared by both elements) ----
    for (int i = tid; i < 16 * 5 * 32; i += 768) {
        const int cc = i & 31, r = i >> 5;          // r = ci*5+k
        w2L[i] = w2[cc * 80 + r];
    }
    for (int i = tid; i < 32 * 3 * 64; i += 768) {
        const int cc = i & 63, r = i >> 6;          // r = ci*3+k
        w3L[i] = w3[cc * 96 + r];
    }
    if (tl < 16) { rm1[e][0][tl] = 0u; rm1[e][1][tl] = 0u; }
    if (tl < 20) { cm2[e][0][tl] = 0u; cm2[e][1][tl] = 0u; }
    if (tl < 8)  { s1e[e][0][384 + tl] = 0.0f; s1e[e][1][384 + tl] = 0.0f; }

    // ---- per-thread register state ----
    float w1r[7];
#pragma unroll
    for (int k = 0; k < 7; ++k) w1r[k] = w1[c1 * 7 + k];
    const float b1r = b1[c1];
    const float b2r = b2[c2];
    const float b3r = b3[c3];
    const float fb1r = (tl < 256) ? fb1[tl] : 0.0f;
    const int jf = tl >> 4, chf = tl & 15;           // fc2 roles (tl<160)
    const float fb2r = (tl < 160 && chf == 0) ? fb2[jf] : 0.0f;

    float m1 = 0.f;
    float m2[2] = {0.f, 0.f};
    float m3[3] = {0.f, 0.f, 0.f};
    float m4 = 0.f, m5 = 0.f;

    const float* xb = x + (2 * b + e) * 3000;
    const int out_b = (2 * b + e) * 10;
    const float4* fw1Tv = reinterpret_cast<const float4*>(fw1T);

    // x for t=0 (loads overlap the staging barrier)
    float xr[7];
#pragma unroll
    for (int k = 0; k < 7; ++k) xr[k] = xb[(l1 + k) * 100];

    __syncthreads();   // staging -> compute

    // ==== prologue ====
    // conv1(0) -> s1e[0], rm1[0]
    {
        float h = b1r;
#pragma unroll
        for (int k = 0; k < 7; ++k) h += xr[k] * w1r[k];
        float rs = (m1 > 1.0f) ? 1.0f : 0.0f;
        m1 = BETA * m1 + h - rs;
        float sa = (m1 > 1.0f) ? 1.0f : 0.0f;
        s1e[e][0][c1 * 24 + l1] = sa;
        if (sa != 0.0f) atomicOr(&rm1[e][0][c1], 1u << l1);
#pragma unroll
        for (int k = 0; k < 7; ++k) xr[k] = xb[(l1 + k) * 100 + 1];   // x(1)
    }
    __syncthreads();
    // conv2(0) [rm1[0], s1e[0] -> cm2[0]]  +  conv1(1) [-> s1e[1], rm1[1]]
    {
        float h[2] = {b2r, b2r};
#pragma unroll
        for (int ci = 0; ci < 16; ++ci) {
            const unsigned rmv = __builtin_amdgcn_readfirstlane(rm1[e][0][ci]);
            if ((rmv & wmask2) == 0u) continue;
            const float2* wp2 = (const float2*)&s1e[e][0][ci * 24 + l02];
            const float2 wa = wp2[0], wb = wp2[1], wc = wp2[2];
            float wk[5];
#pragma unroll
            for (int k = 0; k < 5; ++k) wk[k] = w2L[(ci * 5 + k) * 32 + c2];
            h[0] += wa.x * wk[0]; h[0] += wa.y * wk[1];
            h[0] += wb.x * wk[2]; h[0] += wb.y * wk[3];
            h[0] += wc.x * wk[4];
            h[1] += wa.y * wk[0]; h[1] += wb.x * wk[1];
            h[1] += wb.y * wk[2]; h[1] += wc.x * wk[3];
            h[1] += wc.y * wk[4];
        }
        if (c2on) {
#pragma unroll
            for (int li = 0; li < 2; ++li) {
                float rs = (m2[li] > 1.0f) ? 1.0f : 0.0f;
                m2[li] = BETA * m2[li] + h[li] - rs;
                if (m2[li] > 1.0f) atomicOr(&cm2[e][0][l02 + li], 1u << c2);
            }
        }
        // conv1(1)
        float h1 = b1r;
#pragma unroll
        for (int k = 0; k < 7; ++k) h1 += xr[k] * w1r[k];
        float rs = (m1 > 1.0f) ? 1.0f : 0.0f;
        m1 = BETA * m1 + h1 - rs;
        float sa = (m1 > 1.0f) ? 1.0f : 0.0f;
        s1e[e][1][c1 * 24 + l1] = sa;
        if (sa != 0.0f) atomicOr(&rm1[e][1][c1], 1u << l1);
    }
    __syncthreads();
    // conv3(0): cm2[0] -> masks(0)
    {
        float h[3] = {b3r, b3r, b3r};
#pragma unroll
        for (int wl = 0; wl < 5; ++wl) {
            unsigned cm = __builtin_amdgcn_readfirstlane(cm2[e][0][l03 + wl]);
            while (cm) {
                const int ci = (int)__builtin_ctz(cm); cm &= cm - 1;
                const float* wp = &w3L[ci * 192 + c3];
#pragma unroll
                for (int k = 0; k < 3; ++k) {
                    const int li = wl - k;
                    if (li >= 0 && li < 3) h[li] += wp[k * 64];
                }
            }
        }
#pragma unroll
        for (int li = 0; li < 3; ++li) {
            float rs = (m3[li] > 1.0f) ? 1.0f : 0.0f;
            m3[li] = BETA * m3[li] + h[li] - rs;
            float s = (m3[li] > 1.0f) ? 1.0f : 0.0f;
            unsigned long long mk = __ballot(s != 0.0f);
            if (lane == 0) masks[e][l03 + li] = mk;
        }
    }
    __syncthreads();

    // ==== pipelined main loop ====
    for (int t = 0; t < 100; ++t) {
        const int pi = t & 1;        // parity of t   (conv1(t+2) target)
        const int pc = pi ^ 1;       // parity of t+1 (conv2/conv3 source)

        // ---- Phase A: conv2(t+1) + fc1(t) ----
        if (t < 98) {   // x(t+2) for conv1(t+2) in C (2 phases of latency)
#pragma unroll
            for (int k = 0; k < 7; ++k) xr[k] = xb[(l1 + k) * 100 + t + 2];
        }
        if (t < 99) {
            float h[2] = {b2r, b2r};
#pragma unroll
            for (int ci = 0; ci < 16; ++ci) {
                const unsigned rmv =
                    __builtin_amdgcn_readfirstlane(rm1[e][pc][ci]);
                if ((rmv & wmask2) == 0u) continue;   // exact: skipped terms 0*w
                const float2* wp2 = (const float2*)&s1e[e][pc][ci * 24 + l02];
                const float2 wa = wp2[0], wb = wp2[1], wc = wp2[2];
                float wk[5];
#pragma unroll
                for (int k = 0; k < 5; ++k) wk[k] = w2L[(ci * 5 + k) * 32 + c2];
                h[0] += wa.x * wk[0]; h[0] += wa.y * wk[1];
                h[0] += wb.x * wk[2]; h[0] += wb.y * wk[3];
                h[0] += wc.x * wk[4];
                h[1] += wa.y * wk[0]; h[1] += wb.x * wk[1];
                h[1] += wb.y * wk[2]; h[1] += wc.x * wk[3];
                h[1] += wc.y * wk[4];
            }
            if (c2on) {
#pragma unroll
                for (int li = 0; li < 2; ++li) {
                    float rs = (m2[li] > 1.0f) ? 1.0f : 0.0f;
                    m2[li] = BETA * m2[li] + h[li] - rs;
                    if (m2[li] > 1.0f) atomicOr(&cm2[e][pc][l02 + li], 1u << c2);
                }
            }
        }
        // fc1(t): merged 3-segment scalar walk, 4-wide float4 rounds.
        // Add order = mk0 bits ascending, then mk1, then mk2 == old per-l
        // order -> bit-exact vs R12/R14.
        {
            const int L0 = ew, L1 = ew + 6, L2 = ew + 12;
            const unsigned* q0 = (const unsigned*)&masks[e][L0];
            const unsigned* q1 = (const unsigned*)&masks[e][L1];
            const unsigned* q2 = (const unsigned*)&masks[e][L2];
            unsigned long long mk0 =
                ((unsigned long long)__builtin_amdgcn_readfirstlane(q0[1]) << 32)
                | __builtin_amdgcn_readfirstlane(q0[0]);
            unsigned long long mk1 =
                ((unsigned long long)__builtin_amdgcn_readfirstlane(q1[1]) << 32)
                | __builtin_amdgcn_readfirstlane(q1[0]);
            unsigned long long mk2 =
                ((unsigned long long)__builtin_amdgcn_readfirstlane(q2[1]) << 32)
                | __builtin_amdgcn_readfirstlane(q2[0]);
            float4 acc4; acc4.x = acc4.y = acc4.z = acc4.w = 0.0f;

            auto pull = [&](float4& f) {
                // prioritized branchless select (all scalar state)
                const bool h0 = (mk0 != 0ull), h1 = (mk1 != 0ull);
                unsigned long long sel = h0 ? mk0 : (h1 ? mk1 : mk2);
                const int lsel = h0 ? L0 : (h1 ? L1 : L2);
                if (sel) {
                    const int c = (int)__builtin_ctzll(sel);
                    f = fw1Tv[(c * 18 + lsel) * 64 + lane];
                    const unsigned long long nm = sel & (sel - 1);
                    if (h0) mk0 = nm; else if (h1) mk1 = nm; else mk2 = nm;
                }
            };

            while (mk0 | mk1 | mk2) {
                float4 f0, f1, f2, f3;
                f0.x=f0.y=f0.z=f0.w=0.f; f1=f0; f2=f0; f3=f0;
                pull(f0); pull(f1); pull(f2); pull(f3);
                acc4.x += f0.x; acc4.y += f0.y; acc4.z += f0.z; acc4.w += f0.w;
                acc4.x += f1.x; acc4.y += f1.y; acc4.z += f1.z; acc4.w += f1.w;
                acc4.x += f2.x; acc4.y += f2.y; acc4.z += f2.z; acc4.w += f2.w;
                acc4.x += f3.x; acc4.y += f3.y; acc4.z += f3.z; acc4.w += f3.w;
            }
            ((float4*)&pacc[e][ew][0])[lane] = acc4;
        }
        __syncthreads();   // b1

        // ---- Phase B: conv3(t+1) + reduce(t) + zeroing ----
        if (tl < 16) rm1[e][pi][tl] = 0u;   // next writer: conv1(t+2) in C
        if (tl < 20) cm2[e][pi][tl] = 0u;   // next writer: conv2(t+2) next-A
        if (t < 99) {
            float h[3] = {b3r, b3r, b3r};
#pragma unroll
            for (int wl = 0; wl < 5; ++wl) {
                unsigned cm =
                    __builtin_amdgcn_readfirstlane(cm2[e][pc][l03 + wl]);
                while (cm) {
                    const int ci = (int)__builtin_ctz(cm); cm &= cm - 1;
                    const float* wp = &w3L[ci * 192 + c3];
#pragma unroll
                    for (int k = 0; k < 3; ++k) {
                        const int li = wl - k;
                        if (li >= 0 && li < 3) h[li] += wp[k * 64];
                    }
                }
            }
#pragma unroll
            for (int li = 0; li < 3; ++li) {
                float rs = (m3[li] > 1.0f) ? 1.0f : 0.0f;
                m3[li] = BETA * m3[li] + h[li] - rs;
                float s = (m3[li] > 1.0f) ? 1.0f : 0.0f;
                unsigned long long mk = __ballot(s != 0.0f);
                if (lane == 0) masks[e][l03 + li] = mk;
            }
        }
        if (tl < 256) {   // reduce(t) + LIF4
            float acc = fb1r;
#pragma unroll
            for (int w = 0; w < 6; ++w) acc += pacc[e][w][tl];
            float rs = (m4 > 1.0f) ? 1.0f : 0.0f;
            m4 = BETA * m4 + acc - rs;
            s4[e][tl] = (m4 > 1.0f) ? 1.0f : 0.0f;
        }
        __syncthreads();   // b2

        // ---- Phase C: fc2(t) + conv1(t+2) ----
        if (tl < 160) {
            const float* wrow = fw2 + jf * 256;   // L1-hot (10KB, reused)
            float p = 0.f;
#pragma unroll
            for (int i = 0; i < 16; ++i)
                p += s4[e][i * 16 + chf] * wrow[i * 16 + chf];
            p += __shfl_xor(p, 8, 16);
            p += __shfl_xor(p, 4, 16);
            p += __shfl_xor(p, 2, 16);
            p += __shfl_xor(p, 1, 16);
            if (chf == 0) {
                float h = fb2r + p;
                float rs = (m5 > 1.0f) ? 1.0f : 0.0f;
                m5 = BETA * m5 + h - rs;
                out[t * 10240 + out_b + jf] = (m5 > 1.0f) ? 1.0f : 0.0f;
            }
        }
        if (t < 98) {   // conv1(t+2) -> s1e[pi], rm1[pi]
            float h = b1r;
#pragma unroll
            for (int k = 0; k < 7; ++k) h += xr[k] * w1r[k];
            float rs = (m1 > 1.0f) ? 1.0f : 0.0f;
            m1 = BETA * m1 + h - rs;
            float sa = (m1 > 1.0f) ? 1.0f : 0.0f;
            s1e[e][pi][c1 * 24 + l1] = sa;
            if (sa != 0.0f) atomicOr(&rm1[e][pi][c1], 1u << l1);
        }
        __syncthreads();   // b3
    }
}

extern "C" void kernel_launch(void* const* d_in, const int* in_sizes, int n_in,
                              void* d_out, int out_size, void* d_ws, size_t ws_size,
                              hipStream_t stream) {
    const float* x   = (const float*)d_in[0];
    const float* w1  = (const float*)d_in[1];
    const float* b1  = (const float*)d_in[2];
    const float* w2  = (const float*)d_in[3];
    const float* b2  = (const float*)d_in[4];
    const float* w3  = (const float*)d_in[5];
    const float* b3  = (const float*)d_in[6];
    const float* fw1 = (const float*)d_in[7];
    const float* fb1 = (const float*)d_in[8];
    const float* fw2 = (const float*)d_in[9];
    const float* fb2 = (const float*)d_in[10];
    float* out  = (float*)d_out;
    float* fw1T = (float*)d_ws;   // 1152*256*4 = 1.18 MB

    dim3 tb(32, 8);
    dim3 tg(1152 / 32, 256 / 32);
    transpose_fw1<<<tg, tb, 0, stream>>>(fw1, fw1T);
    snn_main<<<512, 768, 0, stream>>>(x, w1, b1, w2, b2, w3, b3,
                                      fw1T, fb1, fw2, fb2, out);
}

// Round 16
// 615.445 us; speedup vs baseline: 2.4919x; 2.4919x over previous
//
#include <hip/hip_runtime.h>
#include <stdint.h>

#define BETA 0.9f

// ---------------------------------------------------------------------------
// Kernel 1: transpose fw1 (256, 1152) -> fw1T (1152, 256) so the fc1 spike
// row-gather is coalesced (row i = 256 contiguous floats = 1KB).
// ---------------------------------------------------------------------------
__global__ void transpose_fw1(const float* __restrict__ A, float* __restrict__ At) {
    __shared__ float tile[32][33];
    const int i0 = blockIdx.x * 32;   // i dim (1152)
    const int j0 = blockIdx.y * 32;   // j dim (256)
    const int tx = threadIdx.x, ty = threadIdx.y;
    for (int r = ty; r < 32; r += 8)
        tile[r][tx] = A[(j0 + r) * 1152 + i0 + tx];      // coalesced read over i
    __syncthreads();
    for (int r = ty; r < 32; r += 8)
        At[(i0 + r) * 256 + j0 + tx] = tile[tx][r];      // coalesced write over j
}

// ---------------------------------------------------------------------------
// Kernel 2: whole SNN. R16 = R12 (best measured: 590us/dispatch) with ONE
// change: conv2 window reads reverted to scalar win[6] (R11 form, same FMA
// order -> bit-exact). Diagnostic: if R12's float2 pointer-cast caused the
// ~3MB scratch (WRITE 7872 vs clean 4800), this clears it.
// fc1 is FROZEN in the R12 minimal form: R13/R15 proved any added live state
// (rank math, merged-walk selects) spills under the pinned ~40-VGPR budget.
// ---------------------------------------------------------------------------
__global__ __launch_bounds__(768)
__attribute__((amdgpu_waves_per_eu(6)))
void snn_main(
    const float* __restrict__ x,      // (1024, 1, 30, 100)
    const float* __restrict__ w1, const float* __restrict__ b1,
    const float* __restrict__ w2, const float* __restrict__ b2,
    const float* __restrict__ w3, const float* __restrict__ b3,
    const float* __restrict__ fw1T,   // (1152, 256) transposed
    const float* __restrict__ fb1,
    const float* __restrict__ fw2, const float* __restrict__ fb2,
    float* __restrict__ out)          // (100, 1024, 10)
{
    const int b    = blockIdx.x;
    const int tid  = threadIdx.x;
    const int e    = (tid >= 384) ? 1 : 0;   // element slot (waves 0-5 / 6-11)
    const int tl   = tid - 384 * e;          // per-element thread id (0..383)
    const int lane = tid & 63;               // hw-wave lane
    const int ew   = tl >> 6;                // per-element wave 0..5

    __shared__ float w2L[16 * 5 * 32];  // [(ci*5+k)*32 + c2]  10 KB (shared)
    __shared__ float w3L[32 * 3 * 64];  // [(ci*3+k)*64 + c3]  24 KB (shared)
    __shared__ float pacc[2][6][256];   // fc1 per-wave partials  12 KB
    __shared__ float s1e[2][16 * 24 + 8];
    __shared__ float s4[2][256];
    __shared__ unsigned long long masks[2][18];  // s3 spikes (bit = channel)
    __shared__ unsigned int rm1[2][2][16];  // s1 row masks (bit l), t-parity
    __shared__ unsigned int cm2[2][2][20];  // s2 per-l channel masks, t-parity

    // ---- static per-thread roles (within element, 6 waves) ----
    const int c1 = tl & 15;             // conv1: channel (all 384 active)
    const int l1 = tl >> 4;             // conv1: l (0..23), exactly one each
    const int c2 = tl & 31;             // conv2: channel
    const int g2 = tl >> 5;             // conv2: l-group 0..11 (10-11 idle)
    const int l02 = 2 * g2;             // pair start
    const bool c2on = (g2 < 10);        // wave-5 halves idle (uniform per half)
    const unsigned wmask2 = c2on ? (0x3Fu << l02) : 0u;
    const int c3 = lane;                // conv3: out channel
    const int l03 = ew * 3;             // conv3: 3 positions per wave (uniform)

    // ---- stage weights into LDS (shared by both elements) ----
    for (int i = tid; i < 16 * 5 * 32; i += 768) {
        const int cc = i & 31, r = i >> 5;          // r = ci*5+k
        w2L[i] = w2[cc * 80 + r];
    }
    for (int i = tid; i < 32 * 3 * 64; i += 768) {
        const int cc = i & 63, r = i >> 6;          // r = ci*3+k
        w3L[i] = w3[cc * 96 + r];
    }
    if (tl < 16) { rm1[e][0][tl] = 0u; rm1[e][1][tl] = 0u; }
    if (tl < 20) { cm2[e][0][tl] = 0u; cm2[e][1][tl] = 0u; }
    if (tl < 8)  s1e[e][384 + tl] = 0.0f;

    // ---- per-thread register state ----
    float w1r[7];
#pragma unroll
    for (int k = 0; k < 7; ++k) w1r[k] = w1[c1 * 7 + k];
    const float b1r = b1[c1];
    const float b2r = b2[c2];
    const float b3r = b3[c3];
    const float fb1r = (tl < 256) ? fb1[tl] : 0.0f;
    const int jf = tl >> 4, chf = tl & 15;           // fc2 roles (tl<160)
    const float fb2r = (tl < 160 && chf == 0) ? fb2[jf] : 0.0f;

    float m1 = 0.f;
    float m2[2] = {0.f, 0.f};
    float m3[3] = {0.f, 0.f, 0.f};
    float m4 = 0.f, m5 = 0.f;

    const float* xb = x + (2 * b + e) * 3000;
    const int out_b = (2 * b + e) * 10;
    const float4* fw1Tv = reinterpret_cast<const float4*>(fw1T);

    // x register load for t=0 (overlaps the staging barrier)
    float xr[7];
#pragma unroll
    for (int k = 0; k < 7; ++k) xr[k] = xb[(l1 + k) * 100];

    __syncthreads();   // staging -> compute

    // ---- peeled conv1(t=0) ----
    {
        float h = b1r;
#pragma unroll
        for (int k = 0; k < 7; ++k) h += xr[k] * w1r[k];
        float rs = (m1 > 1.0f) ? 1.0f : 0.0f;
        m1 = BETA * m1 + h - rs;
        float sa = (m1 > 1.0f) ? 1.0f : 0.0f;
        s1e[e][c1 * 24 + l1] = sa;
        if (sa != 0.0f) atomicOr(&rm1[e][0][c1], 1u << l1);
    }
    __syncthreads();   // conv1(0) -> conv2(0)

    for (int t = 0; t < 100; ++t) {
        const int pb = t & 1, pn = pb ^ 1;

        // ---- conv2 + LIF2 (rm1 row-skip, scalar win reads) ----
        {
            if (tl < 16) rm1[e][pn][tl] = 0u;   // zero other parity for t+1
            if (tl < 20) cm2[e][pn][tl] = 0u;
            // issue x(t+1) loads early: consumed by conv1(t+1) after b3
            if (t < 99) {
#pragma unroll
                for (int k = 0; k < 7; ++k) xr[k] = xb[(l1 + k) * 100 + t + 1];
            }
            float h[2] = {b2r, b2r};
#pragma unroll
            for (int ci = 0; ci < 16; ++ci) {
                const unsigned rmv =
                    __builtin_amdgcn_readfirstlane(rm1[e][pb][ci]);
                if ((rmv & wmask2) == 0u) continue;   // exact: skipped terms 0*w
                float win[6];
#pragma unroll
                for (int r = 0; r < 6; ++r) win[r] = s1e[e][ci * 24 + l02 + r];
                float wk[5];
#pragma unroll
                for (int k = 0; k < 5; ++k) wk[k] = w2L[(ci * 5 + k) * 32 + c2];
#pragma unroll
                for (int li = 0; li < 2; ++li)
#pragma unroll
                    for (int k = 0; k < 5; ++k) h[li] += win[li + k] * wk[k];
            }
            if (c2on) {
#pragma unroll
                for (int li = 0; li < 2; ++li) {
                    float rs = (m2[li] > 1.0f) ? 1.0f : 0.0f;
                    m2[li] = BETA * m2[li] + h[li] - rs;
                    if (m2[li] > 1.0f) atomicOr(&cm2[e][pb][l02 + li], 1u << c2);
                }
            }
        }
        __syncthreads();   // b2

        // ---- conv3 + LIF3: spike-driven gather (wave-uniform, nl3=3) ----
        {
            float h[3] = {b3r, b3r, b3r};
#pragma unroll
            for (int wl = 0; wl < 5; ++wl) {   // window positions l03..l03+4
                unsigned cm = __builtin_amdgcn_readfirstlane(cm2[e][pb][l03 + wl]);
                while (cm) {               // scalar mask walk
                    const int ci = (int)__builtin_ctz(cm); cm &= cm - 1;
                    const float* wp = &w3L[ci * 192 + c3];   // + k*64
#pragma unroll
                    for (int k = 0; k < 3; ++k) {
                        const int li = wl - k;               // compile-time
                        if (li >= 0 && li < 3)
                            h[li] += wp[k * 64];             // ds_read imm offset
                    }
                }
            }
#pragma unroll
            for (int li = 0; li < 3; ++li) {
                float rs = (m3[li] > 1.0f) ? 1.0f : 0.0f;
                m3[li] = BETA * m3[li] + h[li] - rs;
                float s = (m3[li] > 1.0f) ? 1.0f : 0.0f;
                unsigned long long mk = __ballot(s != 0.0f);
                if (lane == 0) masks[e][l03 + li] = mk;
            }
        }
        __syncthreads();   // b3

        // ---- conv1(t+1): runs in fc1's region, fills its latency shadow ----
        if (t < 99) {
            float h = b1r;
#pragma unroll
            for (int k = 0; k < 7; ++k) h += xr[k] * w1r[k];
            float rs = (m1 > 1.0f) ? 1.0f : 0.0f;
            m1 = BETA * m1 + h - rs;
            float sa = (m1 > 1.0f) ? 1.0f : 0.0f;
            s1e[e][c1 * 24 + l1] = sa;
            if (sa != 0.0f) atomicOr(&rm1[e][pn][c1], 1u << l1);
        }

        // ---- fc1 sparse: per-wave l-subset (stride 6), float4 row gather
        //      (FROZEN form: minimal live state, no spill) ----
        {
            float4 acc4; acc4.x = acc4.y = acc4.z = acc4.w = 0.0f;
#pragma unroll 1
            for (int l = ew; l < 18; l += 6) {     // wave-uniform trip count
                const unsigned* mp = (const unsigned*)&masks[e][l];
                const unsigned mlo = __builtin_amdgcn_readfirstlane(mp[0]);
                const unsigned mhi = __builtin_amdgcn_readfirstlane(mp[1]);
                unsigned long long mk = ((unsigned long long)mhi << 32) | mlo;
                while (mk) {   // 4-wide float4 batching, whole row per wave
                    float4 f0, f1, f2, f3;
                    f0.x=f0.y=f0.z=f0.w=0.f; f1=f0; f2=f0; f3=f0;
                    int c;
                    c = (int)__builtin_ctzll(mk); mk &= mk - 1;
                    f0 = fw1Tv[(c * 18 + l) * 64 + lane];
                    if (mk) { c = (int)__builtin_ctzll(mk); mk &= mk - 1;
                              f1 = fw1Tv[(c * 18 + l) * 64 + lane]; }
                    if (mk) { c = (int)__builtin_ctzll(mk); mk &= mk - 1;
                              f2 = fw1Tv[(c * 18 + l) * 64 + lane]; }
                    if (mk) { c = (int)__builtin_ctzll(mk); mk &= mk - 1;
                              f3 = fw1Tv[(c * 18 + l) * 64 + lane]; }
                    acc4.x += f0.x; acc4.y += f0.y; acc4.z += f0.z; acc4.w += f0.w;
                    acc4.x += f1.x; acc4.y += f1.y; acc4.z += f1.z; acc4.w += f1.w;
                    acc4.x += f2.x; acc4.y += f2.y; acc4.z += f2.z; acc4.w += f2.w;
                    acc4.x += f3.x; acc4.y += f3.y; acc4.z += f3.z; acc4.w += f3.w;
                }
            }
            ((float4*)&pacc[e][ew][0])[lane] = acc4;   // partial for j=lane*4+k
        }
        __syncthreads();   // b4

        // ---- fc1 reduce + LIF4 (thread tl<256 owns output j=tl) ----
        if (tl < 256) {
            float acc = fb1r;
#pragma unroll
            for (int w = 0; w < 6; ++w) acc += pacc[e][w][tl];
            float rs = (m4 > 1.0f) ? 1.0f : 0.0f;
            m4 = BETA * m4 + acc - rs;
            s4[e][tl] = (m4 > 1.0f) ? 1.0f : 0.0f;
        }
        __syncthreads();   // b5

        // ---- fc2 fused: 10 outputs, 16 lanes each, shuffle reduce ----
        if (tl < 160) {
            const float* wrow = fw2 + jf * 256;   // L1-hot (10KB, reused)
            float p = 0.f;
#pragma unroll
            for (int i = 0; i < 16; ++i)
                p += s4[e][i * 16 + chf] * wrow[i * 16 + chf];
            p += __shfl_xor(p, 8, 16);
            p += __shfl_xor(p, 4, 16);
            p += __shfl_xor(p, 2, 16);
            p += __shfl_xor(p, 1, 16);
            if (chf == 0) {
                float h = fb2r + p;
                float rs = (m5 > 1.0f) ? 1.0f : 0.0f;
                m5 = BETA * m5 + h - rs;
                out[t * 10240 + out_b + jf] = (m5 > 1.0f) ? 1.0f : 0.0f;
            }
        }
        // no trailing barrier: conv2(t+1)'s inputs (s1e, rm1[pn]) were
        // written before b4; its zeroing targets were last read before b2/b3.
    }
}

extern "C" void kernel_launch(void* const* d_in, const int* in_sizes, int n_in,
                              void* d_out, int out_size, void* d_ws, size_t ws_size,
                              hipStream_t stream) {
    const float* x   = (const float*)d_in[0];
    const float* w1  = (const float*)d_in[1];
    const float* b1  = (const float*)d_in[2];
    const float* w2  = (const float*)d_in[3];
    const float* b2  = (const float*)d_in[4];
    const float* w3  = (const float*)d_in[5];
    const float* b3  = (const float*)d_in[6];
    const float* fw1 = (const float*)d_in[7];
    const float* fb1 = (const float*)d_in[8];
    const float* fw2 = (const float*)d_in[9];
    const float* fb2 = (const float*)d_in[10];
    float* out  = (float*)d_out;
    float* fw1T = (float*)d_ws;   // 1152*256*4 = 1.18 MB

    dim3 tb(32, 8);
    dim3 tg(1152 / 32, 256 / 32);
    transpose_fw1<<<tg, tb, 0, stream>>>(fw1, fw1T);
    snn_main<<<512, 768, 0, stream>>>(x, w1, b1, w2, b2, w3, b3,
                                      fw1T, fb1, fw2, fb2, out);
}